// Round 7
// baseline (291.600 us; speedup 1.0000x reference)
//
#include <hip/hip_runtime.h>
#include <math.h>

#define BSZ 4096
#define DIM 1024
#define NST 2900000

constexpr float GAMMA_S   = 0.8f;
constexpr float GAMMA_U   = 0.8f;
constexpr float RHO_I_C   = 0.1f;
constexpr float RHO_T_C   = 0.1f;
constexpr float C_EPS     = 1e-10f;
constexpr float TAU_MIN_C = 0.005f;
constexpr float TAU_MAX_C = 1.0f;
constexpr float GCLIP     = 5.0f;
constexpr float ETA_INIT_C = 0.01f;
constexpr float ETA_MIN_C  = 1e-4f;
constexpr float PI_F       = 3.14159265358979323846f;

typedef __bf16 bf16x8 __attribute__((ext_vector_type(8)));
typedef float  f32x4  __attribute__((ext_vector_type(4)));

__device__ __forceinline__ unsigned short f2bf(float f) {
    unsigned int u = __float_as_uint(f);
    u += 0x7fffu + ((u >> 16) & 1u);
    return (unsigned short)(u >> 16);
}
__device__ __forceinline__ float bf2f(unsigned short s) {
    return __uint_as_float(((unsigned int)s) << 16);
}

// ---------------------------------------------------------------------------
// conv_copy: fp32->bf16 features + bf16-consistent diag dot + gathers +
// zero scalars + the 8-state-array copy (fused here because it is pure
// elementwise: no LDS, no barriers, disjoint writes — deterministic).
// [round-6 lesson: copy fused into the GEMM's block mix tripped the
//  post-timing determinism check; this placement is structurally safe.]
// ---------------------------------------------------------------------------
__global__ __launch_bounds__(256) void conv_copy(const float* __restrict__ imf,
                                                 const float* __restrict__ txf,
                                                 unsigned short* __restrict__ abf,
                                                 unsigned short* __restrict__ bbf,
                                                 const float* __restrict__ tau_I,
                                                 const float* __restrict__ tau_T,
                                                 const float* __restrict__ b_I,
                                                 const float* __restrict__ b_T,
                                                 const int* __restrict__ iid,
                                                 const int* __restrict__ tid_,
                                                 float* diag, float* tauIg, float* tauTg,
                                                 float* obI, float* obT,
                                                 const float* __restrict__ s_I,
                                                 const float* __restrict__ s_T,
                                                 const float* __restrict__ u_I,
                                                 const float* __restrict__ u_T,
                                                 float* __restrict__ scal,
                                                 float* __restrict__ outbase) {
    if (blockIdx.x == 0 && threadIdx.x < 3) scal[threadIdx.x] = 0.f;
    const int w  = threadIdx.x >> 6;
    const int ln = threadIdx.x & 63;
    const int i  = blockIdx.x * 4 + w;          // row
    float dot = 0.f;
#pragma unroll
    for (int k = 0; k < 4; ++k) {
        const int off = i * DIM + k * 256 + ln * 4;
        float4 a = *(const float4*)&imf[off];
        float4 b = *(const float4*)&txf[off];
        ushort4 ra, rb;
        ra.x = f2bf(a.x); ra.y = f2bf(a.y); ra.z = f2bf(a.z); ra.w = f2bf(a.w);
        rb.x = f2bf(b.x); rb.y = f2bf(b.y); rb.z = f2bf(b.z); rb.w = f2bf(b.w);
        *(ushort4*)&abf[off] = ra;
        *(ushort4*)&bbf[off] = rb;
        dot += bf2f(ra.x) * bf2f(rb.x) + bf2f(ra.y) * bf2f(rb.y) +
               bf2f(ra.z) * bf2f(rb.z) + bf2f(ra.w) * bf2f(rb.w);
    }
#pragma unroll
    for (int m = 32; m; m >>= 1) dot += __shfl_xor(dot, m);
    if (ln == 0) {
        diag[i] = dot;
        const int id = iid[i];
        tauIg[i] = tau_I[id];
        obI[i]   = b_I[id];
        const int td = tid_[i];
        tauTg[i] = tau_T[td];
        obT[i]   = b_T[td];
    }

    // ---- state copy (grid-stride, float4 body; dst base out+16387 makes
    //      element offset 1 the first 16B-aligned float4 slot) ----
    const size_t idx = (size_t)blockIdx.x * 256 + threadIdx.x;
    const size_t stride = (size_t)1024 * 256;
    const size_t NV = (NST - 1) / 4;
    const float* srcs[8] = {s_I, s_T, u_I, u_T, b_I, b_T, tau_I, tau_T};
#pragma unroll
    for (int a = 0; a < 8; ++a) {
        const float* s = srcs[a];
        float* d = outbase + (size_t)a * NST;
        for (size_t cidx = idx; cidx < NV; cidx += stride) {
            const size_t e = 1 + 4 * cidx;
            float4 v = make_float4(s[e], s[e + 1], s[e + 2], s[e + 3]);
            *(float4*)&d[e] = v;
        }
        if (idx == 0) d[0] = s[0];
        if (idx < 3)  d[NST - 3 + idx] = s[NST - 3 + idx];
    }
}

// ---------------------------------------------------------------------------
// gemm_softmax: pure bf16 MFMA GEMM with online-softmax epilogue — sim never
// hits memory. 1024 blocks = exactly 4 blocks/CU, uniform residency.
// m97 structure: 128x128 tile, 4 waves x (4x4) 16x16x32 MFMA, BK=32,
// global_load_lds width=16. LDS swizzle keeps bank conflicts at 0.
// ---------------------------------------------------------------------------
__device__ __forceinline__ void async16(const void* g, void* l) {
    __builtin_amdgcn_global_load_lds(
        (const __attribute__((address_space(1))) void*)g,
        (__attribute__((address_space(3))) void*)l, 16, 0, 0);
}

__global__ __launch_bounds__(256) void gemm_softmax(const unsigned short* __restrict__ A,
                                                    const unsigned short* __restrict__ B,
                                                    const float* __restrict__ diag,
                                                    const float* __restrict__ tauIg,
                                                    const float* __restrict__ tauTg,
                                                    float* __restrict__ rpM,
                                                    float* __restrict__ rpE,
                                                    float* __restrict__ rpV,
                                                    float* __restrict__ cpM,
                                                    float* __restrict__ cpE,
                                                    float* __restrict__ cpV) {
    __shared__ unsigned short As[128 * 32];   // 8 KB
    __shared__ unsigned short Bs[128 * 32];   // 8 KB

    const int tid = threadIdx.x;
    const int gid = blockIdx.x;              // 0..1023
    const int bjIdx = gid & 31, biIdx = gid >> 5;
    const int bi = biIdx * 128;
    const int bj = bjIdx * 128;
    const int lane = tid & 63;
    const int wave = tid >> 6;
    const int m_base = (wave >> 1) * 64;
    const int n_base = (wave & 1) * 64;

    // staging: chunk c -> LDS row c>>2, slot c&3; global k-chunk = slot ^ ((row>>1)&3)
    const int c0 = tid, c1 = tid + 256;
    const int r0 = c0 >> 2, kg0 = ((c0 & 3) ^ ((r0 >> 1) & 3)) * 8;
    const int r1 = c1 >> 2, kg1 = ((c1 & 3) ^ ((r1 >> 1) & 3)) * 8;

    f32x4 acc[4][4];
#pragma unroll
    for (int m = 0; m < 4; ++m)
#pragma unroll
        for (int n = 0; n < 4; ++n)
            acc[m][n] = (f32x4){0.f, 0.f, 0.f, 0.f};

    const int mrow = lane & 15;
    const int q    = lane >> 4;

    for (int k0 = 0; k0 < DIM; k0 += 32) {
        __syncthreads();
        async16(&A[(size_t)(bi + r0) * DIM + k0 + kg0], &As[c0 * 8]);
        async16(&A[(size_t)(bi + r1) * DIM + k0 + kg1], &As[c1 * 8]);
        async16(&B[(size_t)(bj + r0) * DIM + k0 + kg0], &Bs[c0 * 8]);
        async16(&B[(size_t)(bj + r1) * DIM + k0 + kg1], &Bs[c1 * 8]);
        __syncthreads();

        bf16x8 af[4], bfr[4];
#pragma unroll
        for (int t = 0; t < 4; ++t) {
            const int rlA = m_base + t * 16 + mrow;
            const int rlB = n_base + t * 16 + mrow;
            af[t]  = *(const bf16x8*)&As[rlA * 32 + (q ^ ((rlA >> 1) & 3)) * 8];
            bfr[t] = *(const bf16x8*)&Bs[rlB * 32 + (q ^ ((rlB >> 1) & 3)) * 8];
        }
#pragma unroll
        for (int mt = 0; mt < 4; ++mt)
#pragma unroll
            for (int nt = 0; nt < 4; ++nt)
                acc[mt][nt] = __builtin_amdgcn_mfma_f32_16x16x32_bf16(
                    af[mt], bfr[nt], acc[mt][nt], 0, 0, 0);
    }

    // ---- online-softmax epilogue ----
    __syncthreads();
    float* prm = (float*)Bs;   // [0..127]=diag row, [128..255]=itau row,
                               // [256..383]=diag col, [384..511]=itau col
    if (tid < 128) {
        prm[tid]       = diag[bi + tid];
        prm[128 + tid] = 1.0f / tauIg[bi + tid];
        prm[256 + tid] = diag[bj + tid];
        prm[384 + tid] = 1.0f / tauTg[bj + tid];
    }
    __syncthreads();

    float* red = (float*)As;   // rowM 0..255, rowE 256..511, rowV 512..767,
                               // colM 768..1023, colE 1024..1279, colV 1280..1535
    const int rowq = (lane >> 4) * 4;

    // image (row) side: C/D layout row = m_base+mt*16+rowq+r, col = lane&15 (+nt*16)
#pragma unroll
    for (int mt = 0; mt < 4; ++mt)
#pragma unroll
        for (int r = 0; r < 4; ++r) {
            const int row_l = m_base + mt * 16 + rowq + r;
            const float dgr = prm[row_l];
            const float itr = prm[128 + row_l];
            float v0 = (acc[mt][0][r] - dgr) * itr;
            float v1 = (acc[mt][1][r] - dgr) * itr;
            float v2 = (acc[mt][2][r] - dgr) * itr;
            float v3 = (acc[mt][3][r] - dgr) * itr;
            float m = fmaxf(fmaxf(v0, v1), fmaxf(v2, v3));
#pragma unroll
            for (int x = 1; x <= 8; x <<= 1) m = fmaxf(m, __shfl_xor(m, x));
            const float e0 = __expf(v0 - m), e1 = __expf(v1 - m);
            const float e2 = __expf(v2 - m), e3 = __expf(v3 - m);
            float se = e0 + e1 + e2 + e3;
            float sv = e0 * v0 + e1 * v1 + e2 * v2 + e3 * v3;
#pragma unroll
            for (int x = 1; x <= 8; x <<= 1) {
                se += __shfl_xor(se, x);
                sv += __shfl_xor(sv, x);
            }
            if ((lane & 15) == 0) {
                const int idx = wave * 64 + mt * 16 + rowq + r;
                red[idx] = m; red[256 + idx] = se; red[512 + idx] = sv;
            }
        }

    // text (col) side
#pragma unroll
    for (int nt = 0; nt < 4; ++nt) {
        const int col_l = n_base + nt * 16 + (lane & 15);
        const float dgc = prm[256 + col_l];
        const float itc = prm[384 + col_l];
        float m = -INFINITY;
#pragma unroll
        for (int mt = 0; mt < 4; ++mt)
#pragma unroll
            for (int r = 0; r < 4; ++r)
                m = fmaxf(m, (acc[mt][nt][r] - dgc) * itc);
        m = fmaxf(m, __shfl_xor(m, 16));
        m = fmaxf(m, __shfl_xor(m, 32));
        float se = 0.f, sv = 0.f;
#pragma unroll
        for (int mt = 0; mt < 4; ++mt)
#pragma unroll
            for (int r = 0; r < 4; ++r) {
                const float v = (acc[mt][nt][r] - dgc) * itc;
                const float e = __expf(v - m);
                se += e; sv += e * v;
            }
        se += __shfl_xor(se, 16); se += __shfl_xor(se, 32);
        sv += __shfl_xor(sv, 16); sv += __shfl_xor(sv, 32);
        if (lane < 16) {
            const int idx = wave * 64 + nt * 16 + lane;
            red[768 + idx] = m; red[1024 + idx] = se; red[1280 + idx] = sv;
        }
    }
    __syncthreads();

    if (tid < 128) {
        const int rg = tid, li = rg & 63;
        const int w0 = (rg >> 6) * 2, w1 = w0 + 1;
        const float mA = red[w0 * 64 + li], mB = red[w1 * 64 + li];
        const float M = fmaxf(mA, mB);
        const float fA = __expf(mA - M), fB = __expf(mB - M);
        const size_t o = (size_t)bjIdx * BSZ + bi + rg;
        rpM[o] = M;
        rpE[o] = red[256 + w0 * 64 + li] * fA + red[256 + w1 * 64 + li] * fB;
        rpV[o] = red[512 + w0 * 64 + li] * fA + red[512 + w1 * 64 + li] * fB;
    } else {
        const int cg = tid - 128, li = cg & 63;
        const int w0 = cg >> 6, w1 = w0 + 2;
        const float mA = red[768 + w0 * 64 + li], mB = red[768 + w1 * 64 + li];
        const float M = fmaxf(mA, mB);
        const float fA = __expf(mA - M), fB = __expf(mB - M);
        const size_t o = (size_t)biIdx * BSZ + bj + cg;
        cpM[o] = M;
        cpE[o] = red[1024 + w0 * 64 + li] * fA + red[1024 + w1 * 64 + li] * fB;
        cpV[o] = red[1280 + w0 * 64 + li] * fA + red[1280 + w1 * 64 + li] * fB;
    }
}

// ---------------------------------------------------------------------------
// Finalize: rescale-combine the 32 softmax partials per row/col, compute all
// per-position outputs, scatter state, atomic-add the 3 scalars.
// ---------------------------------------------------------------------------
__global__ __launch_bounds__(256) void finalize(const float* __restrict__ s_I,
                                                const float* __restrict__ s_T,
                                                const float* __restrict__ u_I,
                                                const float* __restrict__ u_T,
                                                const int* __restrict__ iid,
                                                const int* __restrict__ tid_,
                                                const int* __restrict__ epoch,
                                                const int* __restrict__ maxep,
                                                const float* __restrict__ tauIg,
                                                const float* __restrict__ tauTg,
                                                const float* __restrict__ obI,
                                                const float* __restrict__ obT,
                                                const float* __restrict__ rpM,
                                                const float* __restrict__ rpE,
                                                const float* __restrict__ rpV,
                                                const float* __restrict__ cpM,
                                                const float* __restrict__ cpE,
                                                const float* __restrict__ cpV,
                                                float* __restrict__ out) {
    const int i = blockIdx.x * 256 + threadIdx.x;

    const float eta = ETA_MIN_C + (ETA_INIT_C - ETA_MIN_C) *
                      cosf(0.5f * PI_F * ((float)epoch[0] / (float)maxep[0]));
    const float invBm1 = 1.0f / (float)(BSZ - 1);
    const float invB   = 1.0f / (float)BSZ;

    float* o_gI   = out;
    float* o_gT   = out + BSZ;
    float* o_gti  = out + 2 * BSZ;
    float* o_gtt  = out + 3 * BSZ;
    float* o_sI   = out + 4 * BSZ + 3;
    float* o_sT   = o_sI + NST;
    float* o_uI   = o_sT + NST;
    float* o_uT   = o_uI + NST;
    float* o_bI   = o_uT + NST;
    float* o_bT   = o_bI + NST;
    float* o_tauI = o_bT + NST;
    float* o_tauT = o_tauI + NST;

    float lossc, tI_B, tT_B;

    // image side
    {
        const int id = iid[i];
        float mr = -INFINITY;
#pragma unroll
        for (int k = 0; k < 32; ++k) mr = fmaxf(mr, rpM[(size_t)k * BSZ + i]);
        const float tau = tauIg[i];
        const float ob = obI[i];
        const float nb = fmaxf(ob, mr);
        float se = 0.f, sv = 0.f;
#pragma unroll
        for (int k = 0; k < 32; ++k) {
            const float f = __expf(rpM[(size_t)k * BSZ + i] - nb);
            se += rpE[(size_t)k * BSZ + i] * f;
            sv += rpV[(size_t)k * BSZ + i] * f;
        }
        const float g = se * invBm1;
        const float s_new = (1.f - GAMMA_S) * s_I[id] * __expf(ob - nb) + GAMMA_S * g;
        const float W = sv * invBm1 / (s_new + C_EPS);
        const float grad = logf(s_new) + nb + RHO_I_C - W;
        lossc = tau * W;
        tI_B  = tau * invB;
        const float gc = fminf(fmaxf(grad, -GCLIP), GCLIP);
        const float u_new = (1.f - GAMMA_U) * u_I[id] + GAMMA_U * gc;
        const float tau_new = fminf(fmaxf(tau - eta * u_new, TAU_MIN_C), TAU_MAX_C);
        o_gI[i] = g;
        o_gti[i] = grad;
        o_sI[id] = s_new;
        o_uI[id] = u_new;
        o_bI[id] = nb;
        o_tauI[id] = tau_new;
    }
    // text side
    {
        const int id = tid_[i];
        float mc = -INFINITY;
#pragma unroll
        for (int k = 0; k < 32; ++k) mc = fmaxf(mc, cpM[(size_t)k * BSZ + i]);
        const float tau = tauTg[i];
        const float ob = obT[i];
        const float nb = fmaxf(ob, mc);
        float se = 0.f, sv = 0.f;
#pragma unroll
        for (int k = 0; k < 32; ++k) {
            const float f = __expf(cpM[(size_t)k * BSZ + i] - nb);
            se += cpE[(size_t)k * BSZ + i] * f;
            sv += cpV[(size_t)k * BSZ + i] * f;
        }
        const float g = se * invBm1;
        const float s_new = (1.f - GAMMA_S) * s_T[id] * __expf(ob - nb) + GAMMA_S * g;
        const float W = sv * invBm1 / (s_new + C_EPS);
        const float grad = logf(s_new) + nb + RHO_T_C - W;
        lossc += tau * W;
        tT_B   = tau * invB;
        const float gc = fminf(fmaxf(grad, -GCLIP), GCLIP);
        const float u_new = (1.f - GAMMA_U) * u_T[id] + GAMMA_U * gc;
        const float tau_new = fminf(fmaxf(tau - eta * u_new, TAU_MIN_C), TAU_MAX_C);
        o_gT[i] = g;
        o_gtt[i] = grad;
        o_sT[id] = s_new;
        o_uT[id] = u_new;
        o_bT[id] = nb;
        o_tauT[id] = tau_new;
    }

    // scalars: loss mean, avg taus
    float v0 = lossc * invB, v1 = tI_B, v2 = tT_B;
#pragma unroll
    for (int o = 32; o; o >>= 1) {
        v0 += __shfl_down(v0, o);
        v1 += __shfl_down(v1, o);
        v2 += __shfl_down(v2, o);
    }
    __shared__ float lds[4][3];
    const int wv = threadIdx.x >> 6, ln = threadIdx.x & 63;
    if (ln == 0) { lds[wv][0] = v0; lds[wv][1] = v1; lds[wv][2] = v2; }
    __syncthreads();
    if (threadIdx.x == 0) {
        atomicAdd(&out[4 * BSZ + 0], lds[0][0] + lds[1][0] + lds[2][0] + lds[3][0]);
        atomicAdd(&out[4 * BSZ + 1], lds[0][1] + lds[1][1] + lds[2][1] + lds[3][1]);
        atomicAdd(&out[4 * BSZ + 2], lds[0][2] + lds[1][2] + lds[2][2] + lds[3][2]);
    }
}

// ---------------------------------------------------------------------------
extern "C" void kernel_launch(void* const* d_in, const int* in_sizes, int n_in,
                              void* d_out, int out_size, void* d_ws, size_t ws_size,
                              hipStream_t stream) {
    const float* imf   = (const float*)d_in[0];
    const float* txf   = (const float*)d_in[1];
    const float* s_I   = (const float*)d_in[2];
    const float* s_T   = (const float*)d_in[3];
    const float* tau_I = (const float*)d_in[4];
    const float* tau_T = (const float*)d_in[5];
    const float* u_I   = (const float*)d_in[6];
    const float* u_T   = (const float*)d_in[7];
    const float* b_I   = (const float*)d_in[8];
    const float* b_T   = (const float*)d_in[9];
    const int* iid     = (const int*)d_in[10];
    const int* tid_    = (const int*)d_in[11];
    const int* epoch   = (const int*)d_in[12];
    const int* maxep   = (const int*)d_in[13];

    float* out = (float*)d_out;
    float* ws  = (float*)d_ws;

    float* diag  = ws + 0 * BSZ;
    float* tauIg = ws + 1 * BSZ;
    float* tauTg = ws + 2 * BSZ;
    float* obI   = ws + 3 * BSZ;
    float* obT   = ws + 4 * BSZ;
    float* rpM   = ws + 5 * BSZ;                   // 32 * BSZ each
    float* rpE   = rpM + (size_t)32 * BSZ;
    float* rpV   = rpE + (size_t)32 * BSZ;
    float* cpM   = rpV + (size_t)32 * BSZ;
    float* cpE   = cpM + (size_t)32 * BSZ;
    float* cpV   = cpE + (size_t)32 * BSZ;
    unsigned short* abf = (unsigned short*)(cpV + (size_t)32 * BSZ);
    unsigned short* bbf = abf + (size_t)BSZ * DIM;

    conv_copy<<<BSZ / 4, 256, 0, stream>>>(imf, txf, abf, bbf, tau_I, tau_T, b_I, b_T,
                                           iid, tid_, diag, tauIg, tauTg, obI, obT,
                                           s_I, s_T, u_I, u_T,
                                           out + 4 * BSZ, out + 4 * BSZ + 3);
    gemm_softmax<<<1024, 256, 0, stream>>>(abf, bbf, diag, tauIg, tauTg,
                                           rpM, rpE, rpV, cpM, cpE, cpV);
    finalize<<<BSZ / 256, 256, 0, stream>>>(s_I, s_T, u_I, u_T, iid, tid_, epoch, maxep,
                                            tauIg, tauTg, obI, obT,
                                            rpM, rpE, rpV, cpM, cpE, cpV, out);
}

// Round 8
// 288.991 us; speedup vs baseline: 1.0090x; 1.0090x over previous
//
#include <hip/hip_runtime.h>
#include <math.h>

#define BSZ 4096
#define DIM 1024
#define NST 2900000

constexpr float GAMMA_S   = 0.8f;
constexpr float GAMMA_U   = 0.8f;
constexpr float RHO_I_C   = 0.1f;
constexpr float RHO_T_C   = 0.1f;
constexpr float C_EPS     = 1e-10f;
constexpr float TAU_MIN_C = 0.005f;
constexpr float TAU_MAX_C = 1.0f;
constexpr float GCLIP     = 5.0f;
constexpr float ETA_INIT_C = 0.01f;
constexpr float ETA_MIN_C  = 1e-4f;
constexpr float PI_F       = 3.14159265358979323846f;

typedef __bf16 bf16x8 __attribute__((ext_vector_type(8)));
typedef float  f32x4  __attribute__((ext_vector_type(4)));

__device__ __forceinline__ unsigned short f2bf(float f) {
    unsigned int u = __float_as_uint(f);
    u += 0x7fffu + ((u >> 16) & 1u);
    return (unsigned short)(u >> 16);
}
__device__ __forceinline__ float bf2f(unsigned short s) {
    return __uint_as_float(((unsigned int)s) << 16);
}

// ---------------------------------------------------------------------------
// conv_copy: 2048 blocks. Blocks 0..1023: fp32->bf16 convert + diag dot +
// gathers (one wave per row). ALL blocks: state copy, restructured for ILP —
// two unrolled passes of 8 independent float4 load/store pairs (one
// guaranteed + one guarded chunk per array per thread).
// [round-7 lesson: 1024-block, serial-loop copy was latency-bound at 2.5 TB/s]
// ---------------------------------------------------------------------------
__global__ __launch_bounds__(256) void conv_copy(const float* __restrict__ imf,
                                                 const float* __restrict__ txf,
                                                 unsigned short* __restrict__ abf,
                                                 unsigned short* __restrict__ bbf,
                                                 const float* __restrict__ tau_I,
                                                 const float* __restrict__ tau_T,
                                                 const float* __restrict__ b_I,
                                                 const float* __restrict__ b_T,
                                                 const int* __restrict__ iid,
                                                 const int* __restrict__ tid_,
                                                 float* diag, float* tauIg, float* tauTg,
                                                 float* obI, float* obT,
                                                 const float* __restrict__ s_I,
                                                 const float* __restrict__ s_T,
                                                 const float* __restrict__ u_I,
                                                 const float* __restrict__ u_T,
                                                 float* __restrict__ scal,
                                                 float* __restrict__ outbase) {
    if (blockIdx.x == 0 && threadIdx.x < 3) scal[threadIdx.x] = 0.f;

    if (blockIdx.x < BSZ / 4) {
        const int w  = threadIdx.x >> 6;
        const int ln = threadIdx.x & 63;
        const int i  = blockIdx.x * 4 + w;          // row
        float dot = 0.f;
#pragma unroll
        for (int k = 0; k < 4; ++k) {
            const int off = i * DIM + k * 256 + ln * 4;
            float4 a = *(const float4*)&imf[off];
            float4 b = *(const float4*)&txf[off];
            ushort4 ra, rb;
            ra.x = f2bf(a.x); ra.y = f2bf(a.y); ra.z = f2bf(a.z); ra.w = f2bf(a.w);
            rb.x = f2bf(b.x); rb.y = f2bf(b.y); rb.z = f2bf(b.z); rb.w = f2bf(b.w);
            *(ushort4*)&abf[off] = ra;
            *(ushort4*)&bbf[off] = rb;
            dot += bf2f(ra.x) * bf2f(rb.x) + bf2f(ra.y) * bf2f(rb.y) +
                   bf2f(ra.z) * bf2f(rb.z) + bf2f(ra.w) * bf2f(rb.w);
        }
#pragma unroll
        for (int m = 32; m; m >>= 1) dot += __shfl_xor(dot, m);
        if (ln == 0) {
            diag[i] = dot;
            const int id = iid[i];
            tauIg[i] = tau_I[id];
            obI[i]   = b_I[id];
            const int td = tid_[i];
            tauTg[i] = tau_T[td];
            obT[i]   = b_T[td];
        }
    }

    // ---- state copy: 2048 blocks x 256 threads = 524288 threads.
    //      NV = 724999 chunks per array -> 1 guaranteed + 1 guarded per array.
    const size_t idx = (size_t)blockIdx.x * 256 + threadIdx.x;
    const size_t stride = (size_t)2048 * 256;       // 524288
    const size_t NV = (NST - 1) / 4;                // 724999
    const float* srcs[8] = {s_I, s_T, u_I, u_T, b_I, b_T, tau_I, tau_T};

#pragma unroll
    for (int a = 0; a < 8; ++a) {
        const float* s = srcs[a];
        float* d = outbase + (size_t)a * NST;
        const size_t e = 1 + 4 * idx;
        float4 v = make_float4(s[e], s[e + 1], s[e + 2], s[e + 3]);
        *(float4*)&d[e] = v;
    }
    const size_t idx2 = idx + stride;
    if (idx2 < NV) {
#pragma unroll
        for (int a = 0; a < 8; ++a) {
            const float* s = srcs[a];
            float* d = outbase + (size_t)a * NST;
            const size_t e = 1 + 4 * idx2;
            float4 v = make_float4(s[e], s[e + 1], s[e + 2], s[e + 3]);
            *(float4*)&d[e] = v;
        }
    }
    if (idx < 3) {
#pragma unroll
        for (int a = 0; a < 8; ++a) {
            const float* s = srcs[a];
            float* d = outbase + (size_t)a * NST;
            d[NST - 3 + idx] = s[NST - 3 + idx];
            if (idx == 0) d[0] = s[0];
        }
    }
}

// ---------------------------------------------------------------------------
// gemm_softmax: pure bf16 MFMA GEMM with online-softmax epilogue — sim never
// hits memory. 1024 blocks (4/CU). BK=64 [round-7 lesson: BK=32 gave only 16
// MFMA per barrier drain, MfmaUtil 19.6%]: 32 MFMA/barrier, half the
// barriers, 32 KB LDS still fits 4 blocks/CU. XOR-by-(row&7) slot swizzle
// keeps fragment ds_read_b128 conflict-free.
// ---------------------------------------------------------------------------
__device__ __forceinline__ void async16(const void* g, void* l) {
    __builtin_amdgcn_global_load_lds(
        (const __attribute__((address_space(1))) void*)g,
        (__attribute__((address_space(3))) void*)l, 16, 0, 0);
}

__global__ __launch_bounds__(256) void gemm_softmax(const unsigned short* __restrict__ A,
                                                    const unsigned short* __restrict__ B,
                                                    const float* __restrict__ diag,
                                                    const float* __restrict__ tauIg,
                                                    const float* __restrict__ tauTg,
                                                    float* __restrict__ rpM,
                                                    float* __restrict__ rpE,
                                                    float* __restrict__ rpV,
                                                    float* __restrict__ cpM,
                                                    float* __restrict__ cpE,
                                                    float* __restrict__ cpV) {
    __shared__ unsigned short As[128 * 64];   // 16 KB, [row][64k] with slot swizzle
    __shared__ unsigned short Bs[128 * 64];   // 16 KB

    const int tid = threadIdx.x;
    const int gid = blockIdx.x;              // 0..1023
    const int bjIdx = gid & 31, biIdx = gid >> 5;
    const int bi = biIdx * 128;
    const int bj = bjIdx * 128;
    const int lane = tid & 63;
    const int wave = tid >> 6;
    const int m_base = (wave >> 1) * 64;
    const int n_base = (wave & 1) * 64;

    // staging: 1024 chunks (16B) per matrix per iter; thread handles chunks
    // c = tid + 256*t. chunk c -> row c>>3, phys slot c&7;
    // global k-chunk = (phys ^ (row&7)) (slot swizzle).
    int srow[4], skg[4];
#pragma unroll
    for (int t = 0; t < 4; ++t) {
        const int c = tid + 256 * t;
        srow[t] = c >> 3;
        skg[t]  = ((c & 7) ^ ((c >> 3) & 7)) * 8;
    }

    f32x4 acc[4][4];
#pragma unroll
    for (int m = 0; m < 4; ++m)
#pragma unroll
        for (int n = 0; n < 4; ++n)
            acc[m][n] = (f32x4){0.f, 0.f, 0.f, 0.f};

    const int mrow = lane & 15;
    const int q    = lane >> 4;              // 0..3

    for (int k0 = 0; k0 < DIM; k0 += 64) {
        __syncthreads();
#pragma unroll
        for (int t = 0; t < 4; ++t)
            async16(&A[(size_t)(bi + srow[t]) * DIM + k0 + skg[t]],
                    &As[(tid + 256 * t) * 8]);
#pragma unroll
        for (int t = 0; t < 4; ++t)
            async16(&B[(size_t)(bj + srow[t]) * DIM + k0 + skg[t]],
                    &Bs[(tid + 256 * t) * 8]);
        __syncthreads();

#pragma unroll
        for (int sub = 0; sub < 2; ++sub) {
            bf16x8 af[4], bfr[4];
#pragma unroll
            for (int t = 0; t < 4; ++t) {
                const int rlA = m_base + t * 16 + mrow;
                const int rlB = n_base + t * 16 + mrow;
                const int slA = ((sub * 4 + q) ^ (rlA & 7)) * 8;
                const int slB = ((sub * 4 + q) ^ (rlB & 7)) * 8;
                af[t]  = *(const bf16x8*)&As[rlA * 64 + slA];
                bfr[t] = *(const bf16x8*)&Bs[rlB * 64 + slB];
            }
#pragma unroll
            for (int mt = 0; mt < 4; ++mt)
#pragma unroll
                for (int nt = 0; nt < 4; ++nt)
                    acc[mt][nt] = __builtin_amdgcn_mfma_f32_16x16x32_bf16(
                        af[mt], bfr[nt], acc[mt][nt], 0, 0, 0);
        }
    }

    // ---- online-softmax epilogue ----
    __syncthreads();
    float* prm = (float*)Bs;   // [0..127]=diag row, [128..255]=itau row,
                               // [256..383]=diag col, [384..511]=itau col
    if (tid < 128) {
        prm[tid]       = diag[bi + tid];
        prm[128 + tid] = 1.0f / tauIg[bi + tid];
        prm[256 + tid] = diag[bj + tid];
        prm[384 + tid] = 1.0f / tauTg[bj + tid];
    }
    __syncthreads();

    float* red = (float*)As;   // rowM 0..255, rowE 256..511, rowV 512..767,
                               // colM 768..1023, colE 1024..1279, colV 1280..1535
    const int rowq = (lane >> 4) * 4;

    // image (row) side: C/D layout row = m_base+mt*16+rowq+r, col = lane&15 (+nt*16)
#pragma unroll
    for (int mt = 0; mt < 4; ++mt)
#pragma unroll
        for (int r = 0; r < 4; ++r) {
            const int row_l = m_base + mt * 16 + rowq + r;
            const float dgr = prm[row_l];
            const float itr = prm[128 + row_l];
            float v0 = (acc[mt][0][r] - dgr) * itr;
            float v1 = (acc[mt][1][r] - dgr) * itr;
            float v2 = (acc[mt][2][r] - dgr) * itr;
            float v3 = (acc[mt][3][r] - dgr) * itr;
            float m = fmaxf(fmaxf(v0, v1), fmaxf(v2, v3));
#pragma unroll
            for (int x = 1; x <= 8; x <<= 1) m = fmaxf(m, __shfl_xor(m, x));
            const float e0 = __expf(v0 - m), e1 = __expf(v1 - m);
            const float e2 = __expf(v2 - m), e3 = __expf(v3 - m);
            float se = e0 + e1 + e2 + e3;
            float sv = e0 * v0 + e1 * v1 + e2 * v2 + e3 * v3;
#pragma unroll
            for (int x = 1; x <= 8; x <<= 1) {
                se += __shfl_xor(se, x);
                sv += __shfl_xor(sv, x);
            }
            if ((lane & 15) == 0) {
                const int idx = wave * 64 + mt * 16 + rowq + r;
                red[idx] = m; red[256 + idx] = se; red[512 + idx] = sv;
            }
        }

    // text (col) side
#pragma unroll
    for (int nt = 0; nt < 4; ++nt) {
        const int col_l = n_base + nt * 16 + (lane & 15);
        const float dgc = prm[256 + col_l];
        const float itc = prm[384 + col_l];
        float m = -INFINITY;
#pragma unroll
        for (int mt = 0; mt < 4; ++mt)
#pragma unroll
            for (int r = 0; r < 4; ++r)
                m = fmaxf(m, (acc[mt][nt][r] - dgc) * itc);
        m = fmaxf(m, __shfl_xor(m, 16));
        m = fmaxf(m, __shfl_xor(m, 32));
        float se = 0.f, sv = 0.f;
#pragma unroll
        for (int mt = 0; mt < 4; ++mt)
#pragma unroll
            for (int r = 0; r < 4; ++r) {
                const float v = (acc[mt][nt][r] - dgc) * itc;
                const float e = __expf(v - m);
                se += e; sv += e * v;
            }
        se += __shfl_xor(se, 16); se += __shfl_xor(se, 32);
        sv += __shfl_xor(sv, 16); sv += __shfl_xor(sv, 32);
        if (lane < 16) {
            const int idx = wave * 64 + nt * 16 + lane;
            red[768 + idx] = m; red[1024 + idx] = se; red[1280 + idx] = sv;
        }
    }
    __syncthreads();

    if (tid < 128) {
        const int rg = tid, li = rg & 63;
        const int w0 = (rg >> 6) * 2, w1 = w0 + 1;
        const float mA = red[w0 * 64 + li], mB = red[w1 * 64 + li];
        const float M = fmaxf(mA, mB);
        const float fA = __expf(mA - M), fB = __expf(mB - M);
        const size_t o = (size_t)bjIdx * BSZ + bi + rg;
        rpM[o] = M;
        rpE[o] = red[256 + w0 * 64 + li] * fA + red[256 + w1 * 64 + li] * fB;
        rpV[o] = red[512 + w0 * 64 + li] * fA + red[512 + w1 * 64 + li] * fB;
    } else {
        const int cg = tid - 128, li = cg & 63;
        const int w0 = cg >> 6, w1 = w0 + 2;
        const float mA = red[768 + w0 * 64 + li], mB = red[768 + w1 * 64 + li];
        const float M = fmaxf(mA, mB);
        const float fA = __expf(mA - M), fB = __expf(mB - M);
        const size_t o = (size_t)biIdx * BSZ + bj + cg;
        cpM[o] = M;
        cpE[o] = red[1024 + w0 * 64 + li] * fA + red[1024 + w1 * 64 + li] * fB;
        cpV[o] = red[1280 + w0 * 64 + li] * fA + red[1280 + w1 * 64 + li] * fB;
    }
}

// ---------------------------------------------------------------------------
// Finalize: rescale-combine the 32 softmax partials per row/col, compute all
// per-position outputs, scatter state, atomic-add the 3 scalars.
// ---------------------------------------------------------------------------
__global__ __launch_bounds__(256) void finalize(const float* __restrict__ s_I,
                                                const float* __restrict__ s_T,
                                                const float* __restrict__ u_I,
                                                const float* __restrict__ u_T,
                                                const int* __restrict__ iid,
                                                const int* __restrict__ tid_,
                                                const int* __restrict__ epoch,
                                                const int* __restrict__ maxep,
                                                const float* __restrict__ tauIg,
                                                const float* __restrict__ tauTg,
                                                const float* __restrict__ obI,
                                                const float* __restrict__ obT,
                                                const float* __restrict__ rpM,
                                                const float* __restrict__ rpE,
                                                const float* __restrict__ rpV,
                                                const float* __restrict__ cpM,
                                                const float* __restrict__ cpE,
                                                const float* __restrict__ cpV,
                                                float* __restrict__ out) {
    const int i = blockIdx.x * 256 + threadIdx.x;

    const float eta = ETA_MIN_C + (ETA_INIT_C - ETA_MIN_C) *
                      cosf(0.5f * PI_F * ((float)epoch[0] / (float)maxep[0]));
    const float invBm1 = 1.0f / (float)(BSZ - 1);
    const float invB   = 1.0f / (float)BSZ;

    float* o_gI   = out;
    float* o_gT   = out + BSZ;
    float* o_gti  = out + 2 * BSZ;
    float* o_gtt  = out + 3 * BSZ;
    float* o_sI   = out + 4 * BSZ + 3;
    float* o_sT   = o_sI + NST;
    float* o_uI   = o_sT + NST;
    float* o_uT   = o_uI + NST;
    float* o_bI   = o_uT + NST;
    float* o_bT   = o_bI + NST;
    float* o_tauI = o_bT + NST;
    float* o_tauT = o_tauI + NST;

    float lossc, tI_B, tT_B;

    // image side
    {
        const int id = iid[i];
        float mr = -INFINITY;
#pragma unroll
        for (int k = 0; k < 32; ++k) mr = fmaxf(mr, rpM[(size_t)k * BSZ + i]);
        const float tau = tauIg[i];
        const float ob = obI[i];
        const float nb = fmaxf(ob, mr);
        float se = 0.f, sv = 0.f;
#pragma unroll
        for (int k = 0; k < 32; ++k) {
            const float f = __expf(rpM[(size_t)k * BSZ + i] - nb);
            se += rpE[(size_t)k * BSZ + i] * f;
            sv += rpV[(size_t)k * BSZ + i] * f;
        }
        const float g = se * invBm1;
        const float s_new = (1.f - GAMMA_S) * s_I[id] * __expf(ob - nb) + GAMMA_S * g;
        const float W = sv * invBm1 / (s_new + C_EPS);
        const float grad = logf(s_new) + nb + RHO_I_C - W;
        lossc = tau * W;
        tI_B  = tau * invB;
        const float gc = fminf(fmaxf(grad, -GCLIP), GCLIP);
        const float u_new = (1.f - GAMMA_U) * u_I[id] + GAMMA_U * gc;
        const float tau_new = fminf(fmaxf(tau - eta * u_new, TAU_MIN_C), TAU_MAX_C);
        o_gI[i] = g;
        o_gti[i] = grad;
        o_sI[id] = s_new;
        o_uI[id] = u_new;
        o_bI[id] = nb;
        o_tauI[id] = tau_new;
    }
    // text side
    {
        const int id = tid_[i];
        float mc = -INFINITY;
#pragma unroll
        for (int k = 0; k < 32; ++k) mc = fmaxf(mc, cpM[(size_t)k * BSZ + i]);
        const float tau = tauTg[i];
        const float ob = obT[i];
        const float nb = fmaxf(ob, mc);
        float se = 0.f, sv = 0.f;
#pragma unroll
        for (int k = 0; k < 32; ++k) {
            const float f = __expf(cpM[(size_t)k * BSZ + i] - nb);
            se += cpE[(size_t)k * BSZ + i] * f;
            sv += cpV[(size_t)k * BSZ + i] * f;
        }
        const float g = se * invBm1;
        const float s_new = (1.f - GAMMA_S) * s_T[id] * __expf(ob - nb) + GAMMA_S * g;
        const float W = sv * invBm1 / (s_new + C_EPS);
        const float grad = logf(s_new) + nb + RHO_T_C - W;
        lossc += tau * W;
        tT_B   = tau * invB;
        const float gc = fminf(fmaxf(grad, -GCLIP), GCLIP);
        const float u_new = (1.f - GAMMA_U) * u_T[id] + GAMMA_U * gc;
        const float tau_new = fminf(fmaxf(tau - eta * u_new, TAU_MIN_C), TAU_MAX_C);
        o_gT[i] = g;
        o_gtt[i] = grad;
        o_sT[id] = s_new;
        o_uT[id] = u_new;
        o_bT[id] = nb;
        o_tauT[id] = tau_new;
    }

    // scalars: loss mean, avg taus
    float v0 = lossc * invB, v1 = tI_B, v2 = tT_B;
#pragma unroll
    for (int o = 32; o; o >>= 1) {
        v0 += __shfl_down(v0, o);
        v1 += __shfl_down(v1, o);
        v2 += __shfl_down(v2, o);
    }
    __shared__ float lds[4][3];
    const int wv = threadIdx.x >> 6, ln = threadIdx.x & 63;
    if (ln == 0) { lds[wv][0] = v0; lds[wv][1] = v1; lds[wv][2] = v2; }
    __syncthreads();
    if (threadIdx.x == 0) {
        atomicAdd(&out[4 * BSZ + 0], lds[0][0] + lds[1][0] + lds[2][0] + lds[3][0]);
        atomicAdd(&out[4 * BSZ + 1], lds[0][1] + lds[1][1] + lds[2][1] + lds[3][1]);
        atomicAdd(&out[4 * BSZ + 2], lds[0][2] + lds[1][2] + lds[2][2] + lds[3][2]);
    }
}

// ---------------------------------------------------------------------------
extern "C" void kernel_launch(void* const* d_in, const int* in_sizes, int n_in,
                              void* d_out, int out_size, void* d_ws, size_t ws_size,
                              hipStream_t stream) {
    const float* imf   = (const float*)d_in[0];
    const float* txf   = (const float*)d_in[1];
    const float* s_I   = (const float*)d_in[2];
    const float* s_T   = (const float*)d_in[3];
    const float* tau_I = (const float*)d_in[4];
    const float* tau_T = (const float*)d_in[5];
    const float* u_I   = (const float*)d_in[6];
    const float* u_T   = (const float*)d_in[7];
    const float* b_I   = (const float*)d_in[8];
    const float* b_T   = (const float*)d_in[9];
    const int* iid     = (const int*)d_in[10];
    const int* tid_    = (const int*)d_in[11];
    const int* epoch   = (const int*)d_in[12];
    const int* maxep   = (const int*)d_in[13];

    float* out = (float*)d_out;
    float* ws  = (float*)d_ws;

    float* diag  = ws + 0 * BSZ;
    float* tauIg = ws + 1 * BSZ;
    float* tauTg = ws + 2 * BSZ;
    float* obI   = ws + 3 * BSZ;
    float* obT   = ws + 4 * BSZ;
    float* rpM   = ws + 5 * BSZ;                   // 32 * BSZ each
    float* rpE   = rpM + (size_t)32 * BSZ;
    float* rpV   = rpE + (size_t)32 * BSZ;
    float* cpM   = rpV + (size_t)32 * BSZ;
    float* cpE   = cpM + (size_t)32 * BSZ;
    float* cpV   = cpE + (size_t)32 * BSZ;
    unsigned short* abf = (unsigned short*)(cpV + (size_t)32 * BSZ);
    unsigned short* bbf = abf + (size_t)BSZ * DIM;

    conv_copy<<<2048, 256, 0, stream>>>(imf, txf, abf, bbf, tau_I, tau_T, b_I, b_T,
                                        iid, tid_, diag, tauIg, tauTg, obI, obT,
                                        s_I, s_T, u_I, u_T,
                                        out + 4 * BSZ, out + 4 * BSZ + 3);
    gemm_softmax<<<1024, 256, 0, stream>>>(abf, bbf, diag, tauIg, tauTg,
                                           rpM, rpE, rpV, cpM, cpE, cpV);
    finalize<<<BSZ / 256, 256, 0, stream>>>(s_I, s_T, u_I, u_T, iid, tid_, epoch, maxep,
                                            tauIg, tauTg, obI, obT,
                                            rpM, rpE, rpV, cpM, cpE, cpV, out);
}